// Round 1
// baseline (3403.262 us; speedup 1.0000x reference)
//
#include <hip/hip_runtime.h>

// GraphTransformerDecode: B=16384 batches, P=25, D=256, H=4 (dh=64 == wave64).
// Stage-1 attention has a single key -> softmax == 1 -> Wk1 unused.
// One block per batch, 256 threads, thread d owns channel d end-to-end.

constexpr int D  = 256;
constexpr int NP = 25;

// Batched layernorm over R rows; each thread holds v[p] = row p, channel tid.
// red must be >= R*4*2 floats of shared scratch.
template <int R>
__device__ __forceinline__ void layernorm_rows(float (&v)[R],
                                               const float* __restrict__ g,
                                               const float* __restrict__ b,
                                               int tid, float* red) {
  const int lane = tid & 63;
  const int wv   = tid >> 6;
#pragma unroll
  for (int p = 0; p < R; ++p) {
    float s = v[p];
    float q = v[p] * v[p];
#pragma unroll
    for (int m = 32; m; m >>= 1) {
      s += __shfl_xor(s, m, 64);
      q += __shfl_xor(q, m, 64);
    }
    if (lane == 0) {
      red[(p * 4 + wv) * 2 + 0] = s;
      red[(p * 4 + wv) * 2 + 1] = q;
    }
  }
  __syncthreads();
  const float gg = g[tid];
  const float bb = b[tid];
#pragma unroll
  for (int p = 0; p < R; ++p) {
    float s = red[(p * 4 + 0) * 2] + red[(p * 4 + 1) * 2] +
              red[(p * 4 + 2) * 2] + red[(p * 4 + 3) * 2];
    float q = red[(p * 4 + 0) * 2 + 1] + red[(p * 4 + 1) * 2 + 1] +
              red[(p * 4 + 2) * 2 + 1] + red[(p * 4 + 3) * 2 + 1];
    float m   = s * (1.0f / 256.0f);
    float var = q * (1.0f / 256.0f) - m * m;
    float inv = rsqrtf(var + 1e-5f);
    v[p] = (v[p] - m) * inv * gg + bb;
  }
  __syncthreads();  // red reusable after this
}

__global__ __launch_bounds__(256, 3)
void gt_fused(const float* __restrict__ X,
              const float* __restrict__ S1,
              const float* __restrict__ S2,
              const float* __restrict__ adj1,
              const float* __restrict__ adj2,
              const float* __restrict__ Wq1,
              const float* __restrict__ Wv1,
              const float* __restrict__ Wo1,
              const float* __restrict__ g11, const float* __restrict__ b11,
              const float* __restrict__ g12, const float* __restrict__ b12,
              const float* __restrict__ Wq2,
              const float* __restrict__ Wk2,
              const float* __restrict__ Wv2,
              const float* __restrict__ Wo2,
              const float* __restrict__ g21, const float* __restrict__ b21,
              const float* __restrict__ g22, const float* __restrict__ b22,
              float* __restrict__ out) {
  __shared__ __align__(16) float rowbuf[NP][D];  // Q2 rows, later O rows
  __shared__ __align__(16) float kgbuf[3][D];    // Kg rows
  __shared__ __align__(16) float xs[D];          // X[b]
  __shared__ float red[NP * 4 * 2];              // reduction scratch

  const int b = blockIdx.x;
  const int d = threadIdx.x;

  xs[d] = X[(size_t)b * D + d];
  __syncthreads();

  // ---------- Stage 1 ----------
  // xq = (X @ Wq1)[d], xv = adj1 * (X @ Wv1)[d]
  float xq = 0.f, xv = 0.f;
  for (int k = 0; k < D; k += 4) {
    const float4 xk = *reinterpret_cast<const float4*>(&xs[k]);
    xq = fmaf(xk.x, Wq1[(k + 0) * D + d], xq);
    xq = fmaf(xk.y, Wq1[(k + 1) * D + d], xq);
    xq = fmaf(xk.z, Wq1[(k + 2) * D + d], xq);
    xq = fmaf(xk.w, Wq1[(k + 3) * D + d], xq);
    xv = fmaf(xk.x, Wv1[(k + 0) * D + d], xv);
    xv = fmaf(xk.y, Wv1[(k + 1) * D + d], xv);
    xv = fmaf(xk.z, Wv1[(k + 2) * D + d], xv);
    xv = fmaf(xk.w, Wv1[(k + 3) * D + d], xv);
  }
  xv *= adj1[0];

  // O[q,d] = S1[q]*xq + xv  (single-key attention: softmax==1, residual Qp)
  float o1[3];
#pragma unroll
  for (int q = 0; q < 3; ++q) o1[q] = fmaf(S1[q], xq, xv);

  layernorm_rows<3>(o1, g11, b11, d, red);

  // O = O + relu(O @ Wo1): need rows of O in LDS
#pragma unroll
  for (int q = 0; q < 3; ++q) rowbuf[q][d] = o1[q];
  __syncthreads();

  {
    float r3[3] = {0.f, 0.f, 0.f};
#pragma unroll 1
    for (int k = 0; k < D; k += 4) {
      const float w0 = Wo1[(k + 0) * D + d];
      const float w1 = Wo1[(k + 1) * D + d];
      const float w2 = Wo1[(k + 2) * D + d];
      const float w3 = Wo1[(k + 3) * D + d];
#pragma unroll
      for (int q = 0; q < 3; ++q) {
        const float4 t = *reinterpret_cast<const float4*>(&rowbuf[q][k]);
        r3[q] = fmaf(t.x, w0, r3[q]);
        r3[q] = fmaf(t.y, w1, r3[q]);
        r3[q] = fmaf(t.z, w2, r3[q]);
        r3[q] = fmaf(t.w, w3, r3[q]);
      }
    }
#pragma unroll
    for (int q = 0; q < 3; ++q) o1[q] += fmaxf(r3[q], 0.f);
  }

  layernorm_rows<3>(o1, g12, b12, d, red);  // o1 = scale_liner[:, d]

  // ---------- Stage 2 ----------
  // Q2[p,d] = sum_j S2[p,j]*sl[j,d] ; Kg[i,d] = sum_j adj2[i,j]*sl[j,d]
  {
    float kgc[3];
#pragma unroll
    for (int i = 0; i < 3; ++i)
      kgc[i] = adj2[i * 3 + 0] * o1[0] + adj2[i * 3 + 1] * o1[1] +
               adj2[i * 3 + 2] * o1[2];
#pragma unroll
    for (int p = 0; p < NP; ++p)
      rowbuf[p][d] = S2[p * 3 + 0] * o1[0] + S2[p * 3 + 1] * o1[1] +
                     S2[p * 3 + 2] * o1[2];
#pragma unroll
    for (int i = 0; i < 3; ++i) kgbuf[i][d] = kgc[i];
  }
  __syncthreads();

  // Qp2[p,d] = (Q2 @ Wq2)[p,d]
  float acc[NP];
#pragma unroll
  for (int p = 0; p < NP; ++p) acc[p] = 0.f;
#pragma unroll 1
  for (int k = 0; k < D; k += 4) {
    const float w0 = Wq2[(k + 0) * D + d];
    const float w1 = Wq2[(k + 1) * D + d];
    const float w2 = Wq2[(k + 2) * D + d];
    const float w3 = Wq2[(k + 3) * D + d];
#pragma unroll
    for (int p = 0; p < NP; ++p) {
      const float4 t = *reinterpret_cast<const float4*>(&rowbuf[p][k]);
      acc[p] = fmaf(t.x, w0, acc[p]);
      acc[p] = fmaf(t.y, w1, acc[p]);
      acc[p] = fmaf(t.z, w2, acc[p]);
      acc[p] = fmaf(t.w, w3, acc[p]);
    }
  }

  // Kp[i,d], Vp[i,d]
  float kp[3] = {0.f, 0.f, 0.f};
  float vp[3] = {0.f, 0.f, 0.f};
#pragma unroll 1
  for (int k = 0; k < D; k += 4) {
    const float a0 = Wk2[(k + 0) * D + d];
    const float a1 = Wk2[(k + 1) * D + d];
    const float a2 = Wk2[(k + 2) * D + d];
    const float a3 = Wk2[(k + 3) * D + d];
    const float c0 = Wv2[(k + 0) * D + d];
    const float c1 = Wv2[(k + 1) * D + d];
    const float c2 = Wv2[(k + 2) * D + d];
    const float c3 = Wv2[(k + 3) * D + d];
#pragma unroll
    for (int i = 0; i < 3; ++i) {
      const float4 t = *reinterpret_cast<const float4*>(&kgbuf[i][k]);
      kp[i] = fmaf(t.x, a0, kp[i]);
      kp[i] = fmaf(t.y, a1, kp[i]);
      kp[i] = fmaf(t.z, a2, kp[i]);
      kp[i] = fmaf(t.w, a3, kp[i]);
      vp[i] = fmaf(t.x, c0, vp[i]);
      vp[i] = fmaf(t.y, c1, vp[i]);
      vp[i] = fmaf(t.z, c2, vp[i]);
      vp[i] = fmaf(t.w, c3, vp[i]);
    }
  }

  // Per-head attention: head h == wave (64 channels), 3 keys.
  // score[p,i] = sum_{d in head} Qp2[p,d]*Kp[i,d]; softmax over i; residual.
  {
    const float scale = 0.0625f;  // 1/sqrt(256)
#pragma unroll 1
    for (int p = 0; p < NP; ++p) {
      float s0 = acc[p] * kp[0];
      float s1 = acc[p] * kp[1];
      float s2 = acc[p] * kp[2];
#pragma unroll
      for (int m = 32; m; m >>= 1) {
        s0 += __shfl_xor(s0, m, 64);
        s1 += __shfl_xor(s1, m, 64);
        s2 += __shfl_xor(s2, m, 64);
      }
      s0 *= scale; s1 *= scale; s2 *= scale;
      const float mx = fmaxf(s0, fmaxf(s1, s2));
      const float e0 = __expf(s0 - mx);
      const float e1 = __expf(s1 - mx);
      const float e2 = __expf(s2 - mx);
      const float inv = 1.0f / (e0 + e1 + e2);
      acc[p] = acc[p] + (e0 * vp[0] + e1 * vp[1] + e2 * vp[2]) * inv;
    }
  }

  layernorm_rows<NP>(acc, g21, b21, d, red);

  // O = O + relu(O @ Wo2)
#pragma unroll
  for (int p = 0; p < NP; ++p) rowbuf[p][d] = acc[p];
  __syncthreads();

  {
    float r[NP];
#pragma unroll
    for (int p = 0; p < NP; ++p) r[p] = 0.f;
#pragma unroll 1
    for (int k = 0; k < D; k += 4) {
      const float w0 = Wo2[(k + 0) * D + d];
      const float w1 = Wo2[(k + 1) * D + d];
      const float w2 = Wo2[(k + 2) * D + d];
      const float w3 = Wo2[(k + 3) * D + d];
#pragma unroll
      for (int p = 0; p < NP; ++p) {
        const float4 t = *reinterpret_cast<const float4*>(&rowbuf[p][k]);
        r[p] = fmaf(t.x, w0, r[p]);
        r[p] = fmaf(t.y, w1, r[p]);
        r[p] = fmaf(t.z, w2, r[p]);
        r[p] = fmaf(t.w, w3, r[p]);
      }
    }
#pragma unroll
    for (int p = 0; p < NP; ++p) acc[p] += fmaxf(r[p], 0.f);
  }

  layernorm_rows<NP>(acc, g22, b22, d, red);

  // Store [B, 25, 256]
  float* outp = out + (size_t)b * NP * D + d;
#pragma unroll
  for (int p = 0; p < NP; ++p) outp[p * D] = acc[p];
}

extern "C" void kernel_launch(void* const* d_in, const int* in_sizes, int n_in,
                              void* d_out, int out_size, void* d_ws, size_t ws_size,
                              hipStream_t stream) {
  const float* X    = (const float*)d_in[0];
  const float* S1   = (const float*)d_in[1];
  const float* S2   = (const float*)d_in[2];
  const float* adj1 = (const float*)d_in[3];
  const float* adj2 = (const float*)d_in[4];
  const float* Wq1  = (const float*)d_in[5];
  // d_in[6] = Wk1: unused — stage-1 softmax over a single key is identically 1.
  const float* Wv1  = (const float*)d_in[7];
  const float* Wo1  = (const float*)d_in[8];
  const float* g11  = (const float*)d_in[9];
  const float* b11  = (const float*)d_in[10];
  const float* g12  = (const float*)d_in[11];
  const float* b12  = (const float*)d_in[12];
  const float* Wq2  = (const float*)d_in[13];
  const float* Wk2  = (const float*)d_in[14];
  const float* Wv2  = (const float*)d_in[15];
  const float* Wo2  = (const float*)d_in[16];
  const float* g21  = (const float*)d_in[17];
  const float* b21  = (const float*)d_in[18];
  const float* g22  = (const float*)d_in[19];
  const float* b22  = (const float*)d_in[20];
  // d_in[21] = H (=4), hard-wired: dh=64 == wave64, head == wave.

  const int B = in_sizes[0] / D;  // X is [B, 1, D]
  hipLaunchKernelGGL(gt_fused, dim3(B), dim3(256), 0, stream,
                     X, S1, S2, adj1, adj2, Wq1, Wv1, Wo1,
                     g11, b11, g12, b12, Wq2, Wk2, Wv2, Wo2,
                     g21, b21, g22, b22, (float*)d_out);
}

// Round 2
// 1130.505 us; speedup vs baseline: 3.0104x; 3.0104x over previous
//
#include <hip/hip_runtime.h>

// GraphTransformerDecode — MFMA bf16 restructure.
// B=16384, P=25, D=256, H=4 (dh=64). Stage-1 softmax over 1 key == 1 -> Wk1 dead.
// 2 batches per block; all GEMMs via v_mfma_f32_16x16x32_bf16 with weights
// pre-packed into B-fragment order in d_ws (L2-resident, one 16B load/lane/frag).

typedef __attribute__((ext_vector_type(8))) short bf16x8;  // 8 bf16 = 4 VGPRs
typedef __attribute__((ext_vector_type(4))) float f32x4;

constexpr int D   = 256;
constexpr int AST = 264;   // ubuf row stride in bf16 (16B-aligned rows, even bank spread)
constexpr int KST = 528;   // kvbuf/qvbuf row stride in bf16

__device__ __forceinline__ short f2bf(float f) {
  unsigned u = __builtin_bit_cast(unsigned, f);
  u = (u + 0x7FFFu + ((u >> 16) & 1u)) >> 16;  // RNE
  return (short)u;
}
__device__ __forceinline__ float bf2f(short s) {
  unsigned u = ((unsigned)(unsigned short)s) << 16;
  return __builtin_bit_cast(float, u);
}

// ---------------- weight pre-pack: W[256x256] fp32 -> bf16 B-fragments ----------
// frag elem (nt, s, lane, j) = W[s*32 + (lane>>4)*8 + j][nt*16 + (lane&15)]
// stored at mat*65536 + ((nt*8 + s)*64 + lane)*8 + j
__global__ void pack_weights(const float* __restrict__ Wq1, const float* __restrict__ Wv1,
                             const float* __restrict__ Wo1, const float* __restrict__ Wq2,
                             const float* __restrict__ Wk2, const float* __restrict__ Wv2,
                             const float* __restrict__ Wo2, short* __restrict__ ws) {
  int g = blockIdx.x * 256 + threadIdx.x;  // 7 * 8192 groups
  int mat = g >> 13, r = g & 8191;
  const float* W = (mat == 0) ? Wq1 : (mat == 1) ? Wv1 : (mat == 2) ? Wo1 :
                   (mat == 3) ? Wq2 : (mat == 4) ? Wk2 : (mat == 5) ? Wv2 : Wo2;
  int nt = r >> 9, s = (r >> 6) & 7, lane = r & 63;
  int qd = lane >> 4, mc = lane & 15;
  bf16x8 v;
#pragma unroll
  for (int j = 0; j < 8; ++j) {
    int k = s * 32 + qd * 8 + j;
    v[j] = f2bf(W[k * 256 + nt * 16 + mc]);
  }
  *reinterpret_cast<bf16x8*>(ws + (size_t)g * 8) = v;
}

// ---------------- per-wave GEMM: C = A(ubuf rows, bf16) @ B(packed) ------------
// MT M-tiles (rows mt*16+m), NTW n-tiles for this wave starting at nt0.
// Scatter C (bf16) to dst with given row stride; row valid iff
//   PMODE ? (rr&31)<25 : rr<lim.  SYNCMID: barrier between MFMA and scatter
//   (required when dst aliases the A buffer).
template <int MT, int NTW, bool PMODE, bool SYNCMID>
__device__ __forceinline__ void wave_gemm(const short* __restrict__ ub,
                                          const bf16x8* __restrict__ Bp, int nt0,
                                          int lane, short* __restrict__ dst,
                                          int dstStride, int lim) {
  const int m = lane & 15, q = lane >> 4;
  f32x4 acc[MT][NTW];
#pragma unroll
  for (int mt = 0; mt < MT; ++mt)
#pragma unroll
    for (int n = 0; n < NTW; ++n) acc[mt][n] = (f32x4){0.f, 0.f, 0.f, 0.f};

#pragma unroll
  for (int s = 0; s < 8; ++s) {
    bf16x8 a[MT];
#pragma unroll
    for (int mt = 0; mt < MT; ++mt)
      a[mt] = *reinterpret_cast<const bf16x8*>(ub + (mt * 16 + m) * AST + s * 32 + q * 8);
#pragma unroll
    for (int n = 0; n < NTW; ++n) {
      bf16x8 b = Bp[(nt0 + n) * 512 + s * 64 + lane];
#pragma unroll
      for (int mt = 0; mt < MT; ++mt)
        acc[mt][n] = __builtin_amdgcn_mfma_f32_16x16x32_bf16(a[mt], b, acc[mt][n], 0, 0, 0);
    }
  }
  if (SYNCMID) __syncthreads();
#pragma unroll
  for (int mt = 0; mt < MT; ++mt)
#pragma unroll
    for (int n = 0; n < NTW; ++n)
#pragma unroll
      for (int r = 0; r < 4; ++r) {
        int rr = mt * 16 + q * 4 + r;
        bool ok = PMODE ? ((rr & 31) < 25) : (rr < lim);
        if (ok) dst[rr * dstStride + (nt0 + n) * 16 + m] = f2bf(acc[mt][n][r]);
      }
}

// ---------------- small layernorm (6 rows, shuffle + cross-wave) ---------------
__device__ __forceinline__ void ln6(float (&v)[2][3], const float* __restrict__ g,
                                    const float* __restrict__ b, int tid, float* red) {
  const int lane = tid & 63, wv = tid >> 6;
#pragma unroll
  for (int i = 0; i < 6; ++i) {
    float x = v[i / 3][i % 3];
    float s = x, qq = x * x;
#pragma unroll
    for (int mm = 32; mm; mm >>= 1) {
      s += __shfl_xor(s, mm, 64);
      qq += __shfl_xor(qq, mm, 64);
    }
    if (lane == 0) {
      red[(i * 4 + wv) * 2 + 0] = s;
      red[(i * 4 + wv) * 2 + 1] = qq;
    }
  }
  __syncthreads();
  const float gg = g[tid], bb = b[tid];
#pragma unroll
  for (int i = 0; i < 6; ++i) {
    float s = red[(i * 4 + 0) * 2] + red[(i * 4 + 1) * 2] +
              red[(i * 4 + 2) * 2] + red[(i * 4 + 3) * 2];
    float qq = red[(i * 4 + 0) * 2 + 1] + red[(i * 4 + 1) * 2 + 1] +
               red[(i * 4 + 2) * 2 + 1] + red[(i * 4 + 3) * 2 + 1];
    float mean = s * (1.0f / 256.0f);
    float var  = qq * (1.0f / 256.0f) - mean * mean;
    float inv  = rsqrtf(var + 1e-5f);
    float x = v[i / 3][i % 3];
    v[i / 3][i % 3] = (x - mean) * inv * gg + bb;
  }
  __syncthreads();
}

// ---------------- cooperative row stats over ubuf (64 rows bf16) ---------------
__device__ __forceinline__ void coop_stats(const short* __restrict__ ub, int tid,
                                           float* red, float (*st)[2]) {
  const int rr = tid >> 2, part = tid & 3;
  float s = 0.f, ss = 0.f;
  if ((rr & 31) < 25) {
#pragma unroll
    for (int c = 0; c < 8; ++c) {
      bf16x8 v8 = *reinterpret_cast<const bf16x8*>(ub + rr * AST + part * 64 + c * 8);
#pragma unroll
      for (int j = 0; j < 8; ++j) {
        float f = bf2f(v8[j]);
        s += f;
        ss = fmaf(f, f, ss);
      }
    }
  }
  red[(rr * 4 + part) * 2 + 0] = s;
  red[(rr * 4 + part) * 2 + 1] = ss;
  __syncthreads();
  if (tid < 64) {
    float S = 0.f, SS = 0.f;
#pragma unroll
    for (int i = 0; i < 4; ++i) {
      S  += red[(tid * 4 + i) * 2 + 0];
      SS += red[(tid * 4 + i) * 2 + 1];
    }
    float mean = S * (1.0f / 256.0f);
    float var  = SS * (1.0f / 256.0f) - mean * mean;
    st[tid][0] = mean;
    st[tid][1] = rsqrtf(var + 1e-5f);
  }
}

// ---------------------------------- main ---------------------------------------
__global__ __launch_bounds__(256, 2)
void gt_mfma(const float* __restrict__ X, const float* __restrict__ S1,
             const float* __restrict__ S2, const float* __restrict__ adj1,
             const float* __restrict__ adj2,
             const float* __restrict__ g11, const float* __restrict__ b11,
             const float* __restrict__ g12, const float* __restrict__ b12,
             const float* __restrict__ g21, const float* __restrict__ b21,
             const float* __restrict__ g22, const float* __restrict__ b22,
             const short* __restrict__ wsp, float* __restrict__ out) {
  __shared__ __align__(16) short ubuf[64 * AST];   // A tiles / C scatter (union)
  __shared__ __align__(16) short kvbuf[6 * KST];   // C2 (robuf) then C4 (Kp|Vp)
  __shared__ __align__(16) short qvbuf[2 * KST];   // C1 (xq|xv)
  __shared__ __align__(16) float wbuf[4][64][4];   // softmax weights per head
  __shared__ float stbuf[64][2];                   // row mean / inv
  __shared__ float redbuf[512];                    // reduction scratch

  const int tid = threadIdx.x, lane = tid & 63, wv = tid >> 6;
  const int b0 = blockIdx.x * 2;

  const bf16x8* pQV1 = (const bf16x8*)(wsp + 0 * 65536);  // [Wq1|Wv1], nt 0..31
  const bf16x8* pWo1 = (const bf16x8*)(wsp + 2 * 65536);
  const bf16x8* pWq2 = (const bf16x8*)(wsp + 3 * 65536);
  const bf16x8* pKV2 = (const bf16x8*)(wsp + 4 * 65536);  // [Wk2|Wv2], nt 0..31
  const bf16x8* pWo2 = (const bf16x8*)(wsp + 6 * 65536);

  // ---- phase 0: A1 = X rows (2), zero-fill all pad rows once ----
  float x0 = X[(size_t)(b0 + 0) * D + tid];
  float x1 = X[(size_t)(b0 + 1) * D + tid];
  ubuf[0 * AST + tid] = f2bf(x0);
  ubuf[1 * AST + tid] = f2bf(x1);
#pragma unroll
  for (int rz = 2; rz < 16; ++rz) ubuf[rz * AST + tid] = 0;
#pragma unroll
  for (int rz = 25; rz < 32; ++rz) ubuf[rz * AST + tid] = 0;
#pragma unroll
  for (int rz = 57; rz < 64; ++rz) ubuf[rz * AST + tid] = 0;
  __syncthreads();

  // ---- G1: [X] @ [Wq1|Wv1] -> qvbuf rows {b}, cols 0..511 ----
  wave_gemm<1, 8, false, false>(ubuf, pQV1, wv * 8, lane, qvbuf, KST, 2);
  __syncthreads();

  const float a1 = adj1[0];
  float o1[2][3];
#pragma unroll
  for (int b = 0; b < 2; ++b) {
    float xq = bf2f(qvbuf[b * KST + tid]);
    float xv = bf2f(qvbuf[b * KST + 256 + tid]) * a1;
#pragma unroll
    for (int qq = 0; qq < 3; ++qq) o1[b][qq] = fmaf(S1[qq], xq, xv);
  }
  ln6(o1, g11, b11, tid, redbuf);

  // ---- G2: O1 @ Wo1 -> kvbuf rows {b*3+q} cols 0..255 ----
#pragma unroll
  for (int b = 0; b < 2; ++b)
#pragma unroll
    for (int qq = 0; qq < 3; ++qq) ubuf[(b * 3 + qq) * AST + tid] = f2bf(o1[b][qq]);
  __syncthreads();
  wave_gemm<1, 4, false, false>(ubuf, pWo1, wv * 4, lane, kvbuf, KST, 6);
  __syncthreads();
#pragma unroll
  for (int b = 0; b < 2; ++b)
#pragma unroll
    for (int qq = 0; qq < 3; ++qq)
      o1[b][qq] += fmaxf(bf2f(kvbuf[(b * 3 + qq) * KST + tid]), 0.f);
  ln6(o1, g12, b12, tid, redbuf);  // o1 = scale_liner channel tid

  // ---- G4: Kg @ [Wk2|Wv2] -> kvbuf rows {b*3+i} cols 0..511 ----
#pragma unroll
  for (int b = 0; b < 2; ++b)
#pragma unroll
    for (int i = 0; i < 3; ++i) {
      float kg = adj2[i * 3 + 0] * o1[b][0] + adj2[i * 3 + 1] * o1[b][1] +
                 adj2[i * 3 + 2] * o1[b][2];
      ubuf[(b * 3 + i) * AST + tid] = f2bf(kg);
    }
  __syncthreads();
  wave_gemm<1, 8, false, false>(ubuf, pKV2, wv * 8, lane, kvbuf, KST, 6);
  __syncthreads();

  // ---- A3 = Q2 rows (rr = b*32+p), G3: Q2 @ Wq2 -> ubuf (Qp2) ----
#pragma unroll
  for (int b = 0; b < 2; ++b)
#pragma unroll
    for (int p = 0; p < 25; ++p) {
      float q2 = S2[p * 3 + 0] * o1[b][0] + S2[p * 3 + 1] * o1[b][1] +
                 S2[p * 3 + 2] * o1[b][2];
      ubuf[(b * 32 + p) * AST + tid] = f2bf(q2);
    }
  __syncthreads();
  wave_gemm<4, 4, true, true>(ubuf, pWq2, wv * 4, lane, ubuf, AST, 0);
  __syncthreads();

  // ---- scores via MFMA: per wave, M-tile mt=wv, all 4 heads, N-tile = 3 keys ----
  {
    const int mt = wv, bb = wv >> 1, plb = (wv & 1) * 16;
    const int m = lane & 15, q = lane >> 4;
#pragma unroll
    for (int h = 0; h < 4; ++h) {
      f32x4 sa = (f32x4){0.f, 0.f, 0.f, 0.f};
#pragma unroll
      for (int s = 0; s < 2; ++s) {
        bf16x8 aq = *reinterpret_cast<const bf16x8*>(
            ubuf + (mt * 16 + m) * AST + h * 64 + s * 32 + q * 8);
        bf16x8 bk = (bf16x8){0, 0, 0, 0, 0, 0, 0, 0};
        if (m < 3)
          bk = *reinterpret_cast<const bf16x8*>(
              kvbuf + (bb * 3 + m) * KST + h * 64 + s * 32 + q * 8);
        sa = __builtin_amdgcn_mfma_f32_16x16x32_bf16(aq, bk, sa, 0, 0, 0);
      }
#pragma unroll
      for (int r = 0; r < 4; ++r) {
        float sc = sa[r] * 0.0625f;  // 1/sqrt(256)
        int lb = lane & 48;
        float t0 = __shfl(sc, lb + 0), t1 = __shfl(sc, lb + 1), t2 = __shfl(sc, lb + 2);
        float mx = fmaxf(t0, fmaxf(t1, t2));
        float e0 = __expf(t0 - mx), e1 = __expf(t1 - mx), e2 = __expf(t2 - mx);
        float w = __expf(sc - mx) / (e0 + e1 + e2);
        int pl = plb + q * 4 + r;
        if (m < 3 && pl < 25) wbuf[h][bb * 32 + pl][m] = w;
      }
    }
  }
  __syncthreads();  // wbuf ready; all ubuf/kvbuf score reads done

  // ---- attention apply + residual (per-channel; head of channel tid == wv) ----
  float acc[2][25];
#pragma unroll
  for (int b = 0; b < 2; ++b) {
    float vp0 = bf2f(kvbuf[(b * 3 + 0) * KST + 256 + tid]);
    float vp1 = bf2f(kvbuf[(b * 3 + 1) * KST + 256 + tid]);
    float vp2 = bf2f(kvbuf[(b * 3 + 2) * KST + 256 + tid]);
#pragma unroll
    for (int p = 0; p < 25; ++p) {
      float4 w4 = *reinterpret_cast<const float4*>(&wbuf[wv][b * 32 + p][0]);
      float qpv = bf2f(ubuf[(b * 32 + p) * AST + tid]);
      float x = qpv + w4.x * vp0 + w4.y * vp1 + w4.z * vp2;
      acc[b][p] = x;
      ubuf[(b * 32 + p) * AST + tid] = f2bf(x);  // element-private rewrite
    }
  }
  __syncthreads();

  // ---- LN21 (cooperative stats) ----
  coop_stats(ubuf, tid, redbuf, stbuf);
  __syncthreads();
  {
    const float gg = g21[tid], bb2 = b21[tid];
#pragma unroll
    for (int b = 0; b < 2; ++b)
#pragma unroll
      for (int p = 0; p < 25; ++p) {
        int rr = b * 32 + p;
        acc[b][p] = (acc[b][p] - stbuf[rr][0]) * stbuf[rr][1] * gg + bb2;
      }
  }

  // ---- A5 = normalized O, G5: O @ Wo2 -> ubuf ----
#pragma unroll
  for (int b = 0; b < 2; ++b)
#pragma unroll
    for (int p = 0; p < 25; ++p) ubuf[(b * 32 + p) * AST + tid] = f2bf(acc[b][p]);
  __syncthreads();
  wave_gemm<4, 4, true, true>(ubuf, pWo2, wv * 4, lane, ubuf, AST, 0);
  __syncthreads();

  // ---- O += relu(O@Wo2); LN22; store ----
#pragma unroll
  for (int b = 0; b < 2; ++b)
#pragma unroll
    for (int p = 0; p < 25; ++p) {
      float r = bf2f(ubuf[(b * 32 + p) * AST + tid]);
      float x = acc[b][p] + fmaxf(r, 0.f);
      acc[b][p] = x;
      ubuf[(b * 32 + p) * AST + tid] = f2bf(x);
    }
  __syncthreads();
  coop_stats(ubuf, tid, redbuf, stbuf);
  __syncthreads();
  {
    const float gg = g22[tid], bb2 = b22[tid];
#pragma unroll
    for (int b = 0; b < 2; ++b)
#pragma unroll
      for (int p = 0; p < 25; ++p) {
        int rr = b * 32 + p;
        float v = (acc[b][p] - stbuf[rr][0]) * stbuf[rr][1] * gg + bb2;
        out[((size_t)(b0 + b) * 25 + p) * D + tid] = v;
      }
  }
}

extern "C" void kernel_launch(void* const* d_in, const int* in_sizes, int n_in,
                              void* d_out, int out_size, void* d_ws, size_t ws_size,
                              hipStream_t stream) {
  const float* X    = (const float*)d_in[0];
  const float* S1   = (const float*)d_in[1];
  const float* S2   = (const float*)d_in[2];
  const float* adj1 = (const float*)d_in[3];
  const float* adj2 = (const float*)d_in[4];
  const float* Wq1  = (const float*)d_in[5];
  // d_in[6] = Wk1: dead (stage-1 softmax over one key == 1)
  const float* Wv1  = (const float*)d_in[7];
  const float* Wo1  = (const float*)d_in[8];
  const float* g11  = (const float*)d_in[9];
  const float* b11  = (const float*)d_in[10];
  const float* g12  = (const float*)d_in[11];
  const float* b12  = (const float*)d_in[12];
  const float* Wq2  = (const float*)d_in[13];
  const float* Wk2  = (const float*)d_in[14];
  const float* Wv2  = (const float*)d_in[15];
  const float* Wo2  = (const float*)d_in[16];
  const float* g21  = (const float*)d_in[17];
  const float* b21  = (const float*)d_in[18];
  const float* g22  = (const float*)d_in[19];
  const float* b22  = (const float*)d_in[20];

  short* wsp = (short*)d_ws;  // needs 7*65536*2 = 917504 bytes

  // re-pack weights every launch (d_ws is re-poisoned before each timed call)
  hipLaunchKernelGGL(pack_weights, dim3(224), dim3(256), 0, stream,
                     Wq1, Wv1, Wo1, Wq2, Wk2, Wv2, Wo2, wsp);

  const int B = in_sizes[0] / D;  // X is [B,1,D]
  hipLaunchKernelGGL(gt_mfma, dim3(B / 2), dim3(256), 0, stream,
                     X, S1, S2, adj1, adj2, g11, b11, g12, b12,
                     g21, b21, g22, b22, (const short*)wsp, (float*)d_out);
}